// Round 12
// baseline (495.495 us; speedup 1.0000x reference)
//
#include <hip/hip_runtime.h>

// SpatialStyleModLayer, round 12 (MI355X / gfx950) -- TWO-KERNEL SPLIT
//   mod  = style @ affine_w^T + affine_b + 1
//   out0 = (x * mod) @ W ;  ssq = (mod^2) @ (W^2) ;  out = out0*rsqrt(ssq+eps)+bias
// R4's fused convoy (284us) is ~40% HBM duty and register-capped (three spill
// failures at live>100). Split:
//   kmod: style -> mod, stored in FRAGMENT-PACKED bf16 layout directly from
//         C-frags (512B/instr lane-linear stores; no LDS transpose; 1 barrier).
//         mod[tile T] lives in d_out bytes [T*32768+16384, +16384) -- consumed
//         by kout block T before its epilogue overwrites that region.
//   kout: x + packed mod -> aprep (pure regs) -> a1/a2 LDS -> ph2 (ct-halved,
//         live<=96) -> swizzled LDS epilogue -> coalesced stores. 3 barriers.
// Both kernels are short independent streaming blocks (5 resp. 4 blocks/CU).
// HBM floor 1.02GB/6.3TBps = 163us; target 200-250us total.

#define CH   256
#define BM   32
#define TILE_BYTES 32768    // BM*CH*4 (f32 out tile)
#define MODP_OFF   16384    // BM*CH*2 (bf16 mod tile) parked in upper half
#define EPS  1e-8f

typedef __attribute__((ext_vector_type(4))) float f32x4;
typedef __attribute__((ext_vector_type(8))) short bf16x8;
typedef __attribute__((ext_vector_type(4))) short s16x4;

__device__ __forceinline__ short f2b(float f) {          // f32 -> bf16 RNE (HW cvt)
    __bf16 h = (__bf16)f;
    return __builtin_bit_cast(short, h);
}
__device__ __forceinline__ float b2f(short b) {
    union { unsigned u; float f; } v;
    v.u = ((unsigned)(unsigned short)b) << 16;
    return v.f;
}
// Swizzled byte offset into a 32-row x 512B-row bf16 tile. chunk = 16B unit (0..31).
__device__ __forceinline__ int swz(int row, int chunk) {
    return row * 512 + ((chunk ^ (row & 7)) << 4);
}

// One-time weight prep: wTb[o][i]=bf16(W[i][o]); wT2b[o][i]=bf16(bf16(W)^2);
// affwb[i][s]=bf16(affw[i][s]).
__global__ void prep_kernel(const float* __restrict__ weight,
                            const float* __restrict__ affw,
                            short* __restrict__ wTb, short* __restrict__ wT2b,
                            short* __restrict__ affwb)
{
    int t = threadIdx.x, b = blockIdx.x;
    float w  = weight[t * CH + b];
    short wb = f2b(w);
    float wf = b2f(wb);
    wTb  [b * CH + t] = wb;
    wT2b [b * CH + t] = f2b(wf * wf);
    affwb[b * CH + t] = f2b(affw[b * CH + t]);
}

// ================= kernel A: mod, fragment-packed output =================
__global__ __launch_bounds__(256, 5)
void kmod(const float* __restrict__ style, const float* __restrict__ affb,
          const short* __restrict__ affwb, char* __restrict__ outbytes)
{
    __shared__ __align__(16) char sty[16384];            // [32][256] bf16, swizzled

    const int tid  = threadIdx.x;
    const int lane = tid & 63;
    const int wid  = tid >> 6;           // 0..3; wave owns i in [wid*64, +64)
    const int l15  = lane & 15;
    const int lgrp = lane >> 4;          // 0..3
    const int koff = lgrp << 3;
    const long T   = blockIdx.x;
    const long r0  = T * BM;

    // ---- stage style [32][256] f32 -> bf16 (swizzled b128 writes) ----
    #pragma unroll
    for (int k = 0; k < 4; ++k) {
        int u = (k << 8) + tid;
        int row = u >> 5, ch = u & 31;
        const float* p = style + (r0 + row) * CH + ch * 8;
        f32x4 v0 = *(const f32x4*)p;
        f32x4 v1 = *(const f32x4*)(p + 4);
        bf16x8 o;
        #pragma unroll
        for (int j = 0; j < 8; ++j)
            o[j] = f2b(j < 4 ? v0[j] : v1[j - 4]);
        *(bf16x8*)(sty + swz(row, ch)) = o;
    }
    __syncthreads();                                     // the only barrier

    // ---- mod^T = affwb @ style^T : accm[it][rt], 64 MFMA ----
    f32x4 accm[4][2];
    #pragma unroll
    for (int a = 0; a < 4; ++a)
        #pragma unroll
        for (int b = 0; b < 2; ++b) { accm[a][b][0]=0.f; accm[a][b][1]=0.f; accm[a][b][2]=0.f; accm[a][b][3]=0.f; }

    #pragma unroll
    for (int kc = 0; kc < 8; ++kc) {
        bf16x8 af[4], bs[2];
        #pragma unroll
        for (int it = 0; it < 4; ++it)
            af[it] = *(const bf16x8*)(affwb + (wid * 64 + it * 16 + l15) * CH + kc * 32 + koff);
        #pragma unroll
        for (int rt = 0; rt < 2; ++rt)
            bs[rt] = *(const bf16x8*)(sty + swz(rt * 16 + l15, kc * 4 + lgrp));
        #pragma unroll
        for (int it = 0; it < 4; ++it)
            #pragma unroll
            for (int rt = 0; rt < 2; ++rt)
                accm[it][rt] = __builtin_amdgcn_mfma_f32_16x16x32_bf16(
                    af[it], bs[rt], accm[it][rt], 0, 0, 0);
    }

    // ---- +affb+1, cvt, store packed: unit (wid,it,rt,lane) -> 8B ----
    char* mp = outbytes + T * TILE_BYTES + MODP_OFF;
    #pragma unroll
    for (int it = 0; it < 4; ++it) {
        int i0 = wid * 64 + it * 16 + (lgrp << 2);
        f32x4 ab = *(const f32x4*)(affb + i0);
        #pragma unroll
        for (int rt = 0; rt < 2; ++rt) {
            f32x4 m = accm[it][rt];
            s16x4 o4 = { f2b(m[0] + ab[0] + 1.0f), f2b(m[1] + ab[1] + 1.0f),
                         f2b(m[2] + ab[2] + 1.0f), f2b(m[3] + ab[3] + 1.0f) };
            *(s16x4*)(mp + (((((wid << 2) + it) << 1) + rt) * 64 + lane) * 8) = o4;
        }
    }
}

// ================= kernel B: out0/ssq/demod =================
__global__ __launch_bounds__(256, 4)
void kout(const float* __restrict__ x, const float* __restrict__ bias,
          const short* __restrict__ wTb, const short* __restrict__ wT2b,
          float* out)                     // NOT restrict: mod alias inside
{
    __shared__ __align__(16) char smem[32768];
    char* A_s = smem;                    // a1 [32][256] bf16 swizzled
    char* B_s = smem + 16384;            // a2

    const int tid  = threadIdx.x;
    const int lane = tid & 63;
    const int wid  = tid >> 6;           // 0..3; wave owns o in [wid*64, +64)
    const int l15  = lane & 15;
    const int lgrp = lane >> 4;
    const int koff = lgrp << 3;
    const long T   = blockIdx.x;
    const long r0  = T * BM;
    const char* mp = (const char*)out + T * TILE_BYTES + MODP_OFF;

    // ---- aprep from packed mod + direct x loads (pure registers) ----
    #pragma unroll
    for (int it = 0; it < 4; ++it) {
        int i0 = wid * 64 + it * 16 + (lgrp << 2);
        #pragma unroll
        for (int rt = 0; rt < 2; ++rt) {
            int row = rt * 16 + l15;
            s16x4 mb = *(const s16x4*)(mp + (((((wid << 2) + it) << 1) + rt) * 64 + lane) * 8);
            f32x4 xv = *(const f32x4*)(x + (r0 + row) * CH + i0);
            s16x4 a1v, a2v;
            #pragma unroll
            for (int j = 0; j < 4; ++j) {
                float mf = b2f(mb[j]);
                a1v[j] = f2b(xv[j] * mf);
                a2v[j] = f2b(mf * mf);
            }
            int boff = swz(row, i0 >> 3) + ((i0 & 7) << 1);
            *(s16x4*)(A_s + boff) = a1v;
            *(s16x4*)(B_s + boff) = a2v;
        }
    }
    __syncthreads();                                     // BAR1: a1/a2 visible

    // ---- ph2: acc[2rt][4ct]; ct processed in halves to cap live regs ~96 ----
    f32x4 acc0[2][4], acc1[2][4];
    #pragma unroll
    for (int a = 0; a < 2; ++a)
        #pragma unroll
        for (int b = 0; b < 4; ++b) {
            acc0[a][b][0]=0.f; acc0[a][b][1]=0.f; acc0[a][b][2]=0.f; acc0[a][b][3]=0.f;
            acc1[a][b][0]=0.f; acc1[a][b][1]=0.f; acc1[a][b][2]=0.f; acc1[a][b][3]=0.f;
        }

    #pragma unroll
    for (int kc = 0; kc < 8; ++kc) {
        bf16x8 a1f[2], a2f[2];
        #pragma unroll
        for (int rt = 0; rt < 2; ++rt) {
            a1f[rt] = *(const bf16x8*)(A_s + swz(rt * 16 + l15, kc * 4 + lgrp));
            a2f[rt] = *(const bf16x8*)(B_s + swz(rt * 16 + l15, kc * 4 + lgrp));
        }
        #pragma unroll
        for (int h = 0; h < 2; ++h) {                    // ct halves: {0,1}, {2,3}
            bf16x8 bw[2], bw2[2];
            #pragma unroll
            for (int c = 0; c < 2; ++c) {
                int o = wid * 64 + (h * 2 + c) * 16 + l15;
                bw [c] = *(const bf16x8*)(wTb  + o * CH + kc * 32 + koff);
                bw2[c] = *(const bf16x8*)(wT2b + o * CH + kc * 32 + koff);
            }
            #pragma unroll
            for (int rt = 0; rt < 2; ++rt)
                #pragma unroll
                for (int c = 0; c < 2; ++c) {
                    acc0[rt][h * 2 + c] = __builtin_amdgcn_mfma_f32_16x16x32_bf16(
                        a1f[rt], bw[c],  acc0[rt][h * 2 + c], 0, 0, 0);
                    acc1[rt][h * 2 + c] = __builtin_amdgcn_mfma_f32_16x16x32_bf16(
                        a2f[rt], bw2[c], acc1[rt][h * 2 + c], 0, 0, 0);
                }
        }
    }
    __syncthreads();                                     // BAR2: LDS reads done

    // ---- epilogue: demod+bias -> swizzled f32 stage over whole 32KB ----
    #pragma unroll
    for (int ct = 0; ct < 4; ++ct) {
        int o = wid * 64 + ct * 16 + l15;
        float bsv = bias[o];
        int cO = o >> 2, sub = (o & 3) << 2;
        #pragma unroll
        for (int rt = 0; rt < 2; ++rt)
            #pragma unroll
            for (int j = 0; j < 4; ++j) {
                int r = rt * 16 + (lgrp << 2) + j;
                *(float*)(smem + r * 1024 + ((cO ^ (r & 7)) << 4) + sub) =
                    acc0[rt][ct][j] * rsqrtf(acc1[rt][ct][j] + EPS) + bsv;
            }
    }
    __syncthreads();                                     // BAR3: stage visible

    // ---- coalesced stores (overwrites this tile's mod region -- consumed) ----
    #pragma unroll
    for (int k = 0; k < 8; ++k) {
        int u = (k << 8) + tid;
        int row = u >> 6, c4 = u & 63;
        f32x4 v = *(const f32x4*)(smem + row * 1024 + ((c4 ^ (row & 7)) << 4));
        *(f32x4*)(out + (r0 + row) * CH + c4 * 4) = v;
    }
}

extern "C" void kernel_launch(void* const* d_in, const int* in_sizes, int n_in,
                              void* d_out, int out_size, void* d_ws, size_t ws_size,
                              hipStream_t stream) {
    const float* x      = (const float*)d_in[0];
    const float* style  = (const float*)d_in[1];
    const float* weight = (const float*)d_in[2];
    const float* bias   = (const float*)d_in[3];
    const float* affw   = (const float*)d_in[4];
    const float* affb   = (const float*)d_in[5];

    short* ws    = (short*)d_ws;
    short* wTb   = ws;                 // [256][256] bf16
    short* wT2b  = ws + CH * CH;
    short* affwb = ws + 2 * CH * CH;

    prep_kernel<<<dim3(CH), dim3(CH), 0, stream>>>(weight, affw, wTb, wT2b, affwb);

    const int rows   = 4 * 65536;      // 262144
    const int ntiles = rows / BM;      // 8192

    kmod<<<dim3(ntiles), dim3(256), 0, stream>>>(style, affb, affwb, (char*)d_out);
    kout<<<dim3(ntiles), dim3(256), 0, stream>>>(x, bias, wTb, wT2b, (float*)d_out);
}